// Round 7
// baseline (913.206 us; speedup 1.0000x reference)
//
#include <hip/hip_runtime.h>
#include <hip/hip_bf16.h>

typedef __bf16 bf16_t;
typedef __bf16 bf16x8 __attribute__((ext_vector_type(8)));
typedef float f32x4 __attribute__((ext_vector_type(4)));

// Problem constants
#define T_SEQ 3072
#define DIM 2048
#define NH 16
#define QLORA 1536
#define KVLORA 512
#define NOPE 128
#define ROPE 64
#define VDIM 128
#define HD 192          // NOPE+ROPE
#define SCALE 0.07216878364870323f  // 192^-0.5
#define CHUNK 12        // k-tiles (of 64 keys) per attention block

// ---------------- helpers ----------------
__device__ inline float wave_reduce_sum(float v) {
    #pragma unroll
    for (int off = 32; off > 0; off >>= 1) v += __shfl_down(v, off);
    return v;
}

__device__ inline float block_reduce_sum_256(float v) {
    __shared__ float red[4];
    int lane = threadIdx.x & 63, w = threadIdx.x >> 6;
    v = wave_reduce_sum(v);
    if (lane == 0) red[w] = v;
    __syncthreads();
    if (threadIdx.x == 0) red[0] = red[0] + red[1] + red[2] + red[3];
    __syncthreads();
    return red[0];
}

// ---------------- fp32 -> bf16 convert ----------------
__global__ void f2b_kernel(const float* __restrict__ in, bf16_t* __restrict__ out, int n) {
    int i = (blockIdx.x * 256 + threadIdx.x) * 4;
    if (i < n) {
        float4 v = *(const float4*)&in[i];
        bf16_t o[4] = {(bf16_t)v.x, (bf16_t)v.y, (bf16_t)v.z, (bf16_t)v.w};
        *(uint2*)&out[i] = *(const uint2*)o;
    }
}

// ---------------- fp32 [K][N] -> bf16 [N][K] transpose-convert ----------------
__global__ __launch_bounds__(256) void transp_kernel(
    const float* __restrict__ in, bf16_t* __restrict__ out, int K, int N)
{
    __shared__ float tile[32][33];
    int k0 = blockIdx.y * 32, n0 = blockIdx.x * 32;
    int tx = threadIdx.x & 31, ty = threadIdx.x >> 5;
    #pragma unroll
    for (int i = 0; i < 4; ++i)
        tile[ty + i * 8][tx] = in[(size_t)(k0 + ty + i * 8) * N + n0 + tx];
    __syncthreads();
    #pragma unroll
    for (int i = 0; i < 4; ++i)
        out[(size_t)(n0 + ty + i * 8) * K + k0 + tx] = (bf16_t)tile[tx][ty + i * 8];
}

// ---------------- bf16 kvu V-part -> vt[h][d][t] transpose ----------------
__global__ __launch_bounds__(256) void vt_transp(
    const bf16_t* __restrict__ kvu, bf16_t* __restrict__ vt)
{
    __shared__ bf16_t tile[32][34];
    int t0 = blockIdx.x * 32, d0 = blockIdx.y * 32, h = blockIdx.z;
    int tx = threadIdx.x & 31, ty = threadIdx.x >> 5;
    #pragma unroll
    for (int i = 0; i < 4; ++i)
        tile[ty + i * 8][tx] = kvu[(size_t)(t0 + ty + i * 8) * (NH * 256) + h * 256 + NOPE + d0 + tx];
    __syncthreads();
    #pragma unroll
    for (int i = 0; i < 4; ++i)
        vt[((size_t)h * VDIM + d0 + ty + i * 8) * T_SEQ + t0 + tx] = tile[tx][ty + i * 8];
}

// ---------------- MFMA GEMM: C[M,N] = A[M,K](bf16, row stride lda) x Bt[N,K](bf16) ----------------
__global__ __launch_bounds__(256) void gemm_mfma(
    const bf16_t* __restrict__ A, int lda, const bf16_t* __restrict__ Bt,
    float* __restrict__ Cf, bf16_t* __restrict__ Cb,
    int M, int N, int K, int writef)
{
    __shared__ __align__(16) bf16_t As[128 * 40];
    __shared__ __align__(16) bf16_t Bs[128 * 40];
    int tid = threadIdx.x;
    int w = tid >> 6, lane = tid & 63;
    int quad = lane >> 4, l16 = lane & 15;
    int bm = blockIdx.y * 128, bn = blockIdx.x * 128;
    int wm = (w & 1) * 64, wn = (w >> 1) * 64;

    f32x4 acc[4][4];
    #pragma unroll
    for (int i = 0; i < 4; ++i)
        #pragma unroll
        for (int j = 0; j < 4; ++j)
            acc[i][j] = (f32x4){0.f, 0.f, 0.f, 0.f};

    for (int k0 = 0; k0 < K; k0 += 32) {
        #pragma unroll
        for (int l = 0; l < 2; ++l) {
            int cid = tid + l * 256;
            int row = cid >> 2, ch = cid & 3;
            uint4 av = *(const uint4*)&A[(size_t)(bm + row) * lda + k0 + ch * 8];
            *(uint4*)&As[row * 40 + ch * 8] = av;
            int brow = bn + row;
            uint4 bv = {0u, 0u, 0u, 0u};
            if (brow < N) bv = *(const uint4*)&Bt[(size_t)brow * K + k0 + ch * 8];
            *(uint4*)&Bs[row * 40 + ch * 8] = bv;
        }
        __syncthreads();
        bf16x8 af[4], bfr[4];
        #pragma unroll
        for (int t = 0; t < 4; ++t) {
            af[t]  = *(const bf16x8*)&As[(wm + t * 16 + l16) * 40 + quad * 8];
            bfr[t] = *(const bf16x8*)&Bs[(wn + t * 16 + l16) * 40 + quad * 8];
        }
        #pragma unroll
        for (int i = 0; i < 4; ++i)
            #pragma unroll
            for (int j = 0; j < 4; ++j)
                acc[i][j] = __builtin_amdgcn_mfma_f32_16x16x32_bf16(af[i], bfr[j], acc[i][j], 0, 0, 0);
        __syncthreads();
    }

    #pragma unroll
    for (int i = 0; i < 4; ++i) {
        #pragma unroll
        for (int j = 0; j < 4; ++j) {
            #pragma unroll
            for (int r = 0; r < 4; ++r) {
                int row = bm + wm + i * 16 + quad * 4 + r;
                int col = bn + wn + j * 16 + l16;
                if (col < N) {
                    if (writef) Cf[(size_t)row * N + col] = acc[i][j][r];
                    else        Cb[(size_t)row * N + col] = (bf16_t)acc[i][j][r];
                }
            }
        }
    }
}

// ---------------- rmsnorm in-place over strided rows ----------------
__global__ __launch_bounds__(256) void rmsnorm_rows(
    bf16_t* __restrict__ X, int stride, const float* __restrict__ w, int N)
{
    int row = blockIdx.x;
    bf16_t* x = X + (size_t)row * stride;
    float ss = 0.f;
    for (int i = threadIdx.x; i < N; i += 256) { float v = (float)x[i]; ss += v * v; }
    ss = block_reduce_sum_256(ss);
    float sc = rsqrtf(ss / (float)N + 1e-6f);
    for (int i = threadIdx.x; i < N; i += 256)
        x[i] = (bf16_t)((float)x[i] * sc * w[i]);
}

// ---------------- kv post (src = strided view of combined down-proj) ----------------
__global__ __launch_bounds__(256) void kv_post(
    const bf16_t* __restrict__ kvd, int stride, const float* __restrict__ w,
    const float* __restrict__ freqs,
    bf16_t* __restrict__ ckvn, bf16_t* __restrict__ kr)
{
    int row = blockIdx.x;
    const bf16_t* src = kvd + (size_t)row * stride;
    float ss = 0.f;
    for (int i = threadIdx.x; i < KVLORA; i += 256) { float v = (float)src[i]; ss += v * v; }
    ss = block_reduce_sum_256(ss);
    float sc = rsqrtf(ss / (float)KVLORA + 1e-6f);
    for (int i = threadIdx.x; i < KVLORA; i += 256)
        ckvn[(size_t)row * KVLORA + i] = (bf16_t)((float)src[i] * sc * w[i]);
    if (threadIdx.x < 32) {
        int i = threadIdx.x;
        float f = freqs[row * 32 + i];
        float c = cosf(f), s = sinf(f);
        float x1 = (float)src[KVLORA + 2 * i], x2 = (float)src[KVLORA + 2 * i + 1];
        kr[(size_t)row * ROPE + 2 * i]     = (bf16_t)(x1 * c - x2 * s);
        kr[(size_t)row * ROPE + 2 * i + 1] = (bf16_t)(x1 * s + x2 * c);
    }
}

// ---------------- rope on q_rope view (row stride 3072, cols h*64+2i) ----------------
__global__ void rope_q(bf16_t* __restrict__ qr, const float* __restrict__ freqs) {
    int idx = blockIdx.x * 256 + threadIdx.x;
    if (idx >= T_SEQ * NH * 32) return;
    int t = idx >> 9;
    int rem = idx & 511;
    int h = rem >> 5;
    int i = rem & 31;
    float f = freqs[t * 32 + i];
    float c = cosf(f), s = sinf(f);
    bf16_t* p = qr + (size_t)t * 3072 + h * ROPE + 2 * i;
    float x1 = (float)p[0], x2 = (float)p[1];
    p[0] = (bf16_t)(x1 * c - x2 * s);
    p[1] = (bf16_t)(x1 * s + x2 * c);
}

// ---------------- split-K MFMA flash attention, barrier-free ----------------
// grid (48 qt, 4 chunk, 16 h), block 256 (4 waves, fully independent).
// K and V fragments read directly from global (16B/lane); only LDS use is the
// per-wave P layout round-trip (lgkmcnt wait, no __syncthreads anywhere).
#define P_STRIDE 72     // 64+8 bf16
__device__ inline int slot_base(int qt, int h) {
    int b = qt / CHUNK;
    return h * 120 + qt + 6 * b * (b - 1) + (qt - CHUNK * b) * b;
}
__global__ __launch_bounds__(256) void attn_v5(
    const bf16_t* __restrict__ Qup,   // [T][3072]: cols 0..2047 = q_nope, 2048.. = q_rope
    const bf16_t* __restrict__ KVU, const bf16_t* __restrict__ KR,
    const bf16_t* __restrict__ Vt,
    bf16_t* __restrict__ Opart, float* __restrict__ lpart)
{
    __shared__ __align__(16) bf16_t Ps[4][16 * P_STRIDE]; // 9216 B

    int qt = blockIdx.x, cx = blockIdx.y, h = blockIdx.z;
    if (cx > qt / CHUNK) return;
    int slot = slot_base(qt, h) + cx;
    int kt0 = cx * CHUNK;
    int kt1 = min(qt + 1, kt0 + CHUNK);

    int tid = threadIdx.x;
    int w = tid >> 6, lane = tid & 63;
    int quad = lane >> 4, l16 = lane & 15;
    int qbase = qt * 64;

    // Q fragments (A-operand rows = l16) from global into registers
    bf16x8 qf[6];
    {
        const bf16_t* qp = &Qup[(size_t)(qbase + w * 16 + l16) * 3072];
        #pragma unroll
        for (int kk = 0; kk < 4; ++kk)
            qf[kk] = *(const bf16x8*)&qp[h * NOPE + kk * 32 + quad * 8];
        #pragma unroll
        for (int kk = 4; kk < 6; ++kk)
            qf[kk] = *(const bf16x8*)&qp[2048 + h * ROPE + (kk - 4) * 32 + quad * 8];
    }

    bf16x8 ones;
    #pragma unroll
    for (int i = 0; i < 8; ++i) ones[i] = (bf16_t)1.0f;

    f32x4 o[8];
    #pragma unroll
    for (int nt = 0; nt < 8; ++nt) o[nt] = (f32x4){0.f, 0.f, 0.f, 0.f};
    f32x4 lacc = (f32x4){0.f, 0.f, 0.f, 0.f};

    for (int kt = kt0; kt < kt1; ++kt) {
        int kbase = kt * 64;

        // S = Q K^T : K B-fragments direct from global
        f32x4 S[4];
        #pragma unroll
        for (int c = 0; c < 4; ++c) S[c] = (f32x4){0.f, 0.f, 0.f, 0.f};
        #pragma unroll
        for (int c = 0; c < 4; ++c) {
            int krow = kbase + c * 16 + l16;
            const bf16_t* kpn = &KVU[(size_t)krow * (NH * 256) + h * 256];
            const bf16_t* kpr = &KR[(size_t)krow * ROPE];
            #pragma unroll
            for (int kk = 0; kk < 4; ++kk) {
                bf16x8 kf = *(const bf16x8*)&kpn[kk * 32 + quad * 8];
                S[c] = __builtin_amdgcn_mfma_f32_16x16x32_bf16(qf[kk], kf, S[c], 0, 0, 0);
            }
            #pragma unroll
            for (int kk = 0; kk < 2; ++kk) {
                bf16x8 kf = *(const bf16x8*)&kpr[kk * 32 + quad * 8];
                S[c] = __builtin_amdgcn_mfma_f32_16x16x32_bf16(qf[4 + kk], kf, S[c], 0, 0, 0);
            }
        }

        // fixed-max softmax: p = exp(s*SCALE) (bounded; shift-invariance -> additive splits)
        #pragma unroll
        for (int c = 0; c < 4; ++c) {
            #pragma unroll
            for (int j = 0; j < 4; ++j) {
                int col = kbase + c * 16 + l16;
                int grow = qbase + w * 16 + quad * 4 + j;
                float p = (col <= grow) ? __expf(S[c][j] * SCALE) : 0.f;
                Ps[w][(quad * 4 + j) * P_STRIDE + c * 16 + l16] = (bf16_t)p;
            }
        }
        // wave-internal LDS write->read ordering (per-wave buffer, lockstep wave64)
        __asm__ volatile("s_waitcnt lgkmcnt(0)" ::: "memory");

        bf16x8 pf0 = *(const bf16x8*)&Ps[w][l16 * P_STRIDE + quad * 8];
        bf16x8 pf1 = *(const bf16x8*)&Ps[w][l16 * P_STRIDE + 32 + quad * 8];
        lacc = __builtin_amdgcn_mfma_f32_16x16x32_bf16(pf0, ones, lacc, 0, 0, 0);
        lacc = __builtin_amdgcn_mfma_f32_16x16x32_bf16(pf1, ones, lacc, 0, 0, 0);

        // O += P V : V fragments direct from global vt[h][d][t]
        #pragma unroll
        for (int kk2 = 0; kk2 < 2; ++kk2) {
            bf16x8 pf = kk2 ? pf1 : pf0;
            #pragma unroll
            for (int nt = 0; nt < 8; ++nt) {
                bf16x8 vf = *(const bf16x8*)&Vt[((size_t)h * VDIM + nt * 16 + l16) * T_SEQ + kbase + kk2 * 32 + quad * 8];
                o[nt] = __builtin_amdgcn_mfma_f32_16x16x32_bf16(pf, vf, o[nt], 0, 0, 0);
            }
        }
    }

    // write raw partials (no normalization)
    #pragma unroll
    for (int nt = 0; nt < 8; ++nt)
        #pragma unroll
        for (int j = 0; j < 4; ++j)
            Opart[(size_t)slot * 8192 + (w * 16 + quad * 4 + j) * 128 + nt * 16 + l16] = (bf16_t)o[nt][j];
    if (l16 == 0) {
        #pragma unroll
        for (int j = 0; j < 4; ++j)
            lpart[slot * 64 + w * 16 + quad * 4 + j] = lacc[j];
    }
}

// ---------------- combine: sum partials, normalize, write ao ----------------
__global__ __launch_bounds__(256) void attn_combine(
    const bf16_t* __restrict__ Opart, const float* __restrict__ lpart,
    bf16_t* __restrict__ AO)
{
    int qt = blockIdx.x, h = blockIdx.y;
    int nch = qt / CHUNK + 1;
    int base = slot_base(qt, h);
    int r = threadIdx.x >> 2, c0 = (threadIdx.x & 3) * 32;

    float acc[32];
    #pragma unroll
    for (int i = 0; i < 32; ++i) acc[i] = 0.f;
    float lsum = 0.f;
    for (int ch = 0; ch < nch; ++ch) {
        int slot = base + ch;
        const bf16_t* p = &Opart[(size_t)slot * 8192 + r * 128 + c0];
        #pragma unroll
        for (int v = 0; v < 4; ++v) {
            bf16x8 u = *(const bf16x8*)&p[v * 8];
            #pragma unroll
            for (int e = 0; e < 8; ++e) acc[v * 8 + e] += (float)u[e];
        }
        lsum += lpart[slot * 64 + r];
    }
    float inv = 1.0f / lsum;
    bf16_t* dst = AO + (size_t)(qt * 64 + r) * (NH * VDIM) + h * VDIM + c0;
    #pragma unroll
    for (int v = 0; v < 4; ++v) {
        bf16_t tmp[8];
        #pragma unroll
        for (int e = 0; e < 8; ++e) tmp[e] = (bf16_t)(acc[v * 8 + e] * inv);
        *(uint4*)&dst[v * 8] = *(const uint4*)tmp;
    }
}

// ---------------- launch ----------------
extern "C" void kernel_launch(void* const* d_in, const int* in_sizes, int n_in,
                              void* d_out, int out_size, void* d_ws, size_t ws_size,
                              hipStream_t stream) {
    const float* x        = (const float*)d_in[0];
    const float* freqs    = (const float*)d_in[1];
    // d_in[2] = mask (unused; causality applied analytically)
    const float* wq_down  = (const float*)d_in[3];
    const float* q_norm_w = (const float*)d_in[4];
    const float* wq_nope  = (const float*)d_in[5];
    const float* wq_rope  = (const float*)d_in[6];
    const float* wkv_down = (const float*)d_in[7];
    const float* kv_norm_w= (const float*)d_in[8];
    const float* wkv_up   = (const float*)d_in[9];
    const float* wo       = (const float*)d_in[10];
    float* out = (float*)d_out;

    bf16_t* ws = (bf16_t*)d_ws;
    // ---- pool region (two time-disjoint views), 25,493,504 bf16 elems ----
    // A-view: pre-attention transients
    bf16_t* xb     = ws;                     // 3072*2048
    bf16_t* wqd_t  = xb     + 6291456;       // [1536][2048]  \ adjacent = combined
    bf16_t* wkvd_t = wqd_t  + 3145728;       // [576][2048]   /  Bt [2112][2048]
    bf16_t* wqn_t  = wkvd_t + 1179648;       // [2048][1536]  \ adjacent = combined
    bf16_t* wqr_t  = wqn_t  + 3145728;       // [1024][1536]  /  Bt [3072][1536]
    bf16_t* wkvu_t = wqr_t  + 1572864;       // [4096][512]
    bf16_t* ql_kvd = wkvu_t + 2097152;       // [3072][2112] combined (q_lat | kvd)
    bf16_t* ckvn   = ql_kvd + 6488064;       // 3072*512  (ends at 25,493,504)
    // B-view: attention partials + ao
    bf16_t* Opart  = ws;                     // 1920 slots * 8192
    float*  lpart  = (float*)(ws + 15728640);// 1920 * 64 fp32
    bf16_t* ao     = ws + 15728640 + 245760; // 3072*2048
    // ---- tail region (long-lived) ----
    bf16_t* wo_t   = ws    + 25493504;       // [2048][2048]
    bf16_t* kr     = wo_t  + 4194304;        // 3072*64
    bf16_t* q_up   = kr    + 196608;         // [3072][3072] combined (q_nope | q_rope)
    bf16_t* kvu    = q_up  + 9437184;        // 3072*4096
    bf16_t* vt     = kvu   + 12582912;       // [16][128][3072]  (total 58,195,968)

    // converts + weight transposes
    f2b_kernel<<<T_SEQ * DIM / 4 / 256, 256, 0, stream>>>(x, xb, T_SEQ * DIM);
    transp_kernel<<<dim3(QLORA / 32, DIM / 32), 256, 0, stream>>>(wq_down, wqd_t, DIM, QLORA);
    transp_kernel<<<dim3((KVLORA + ROPE) / 32, DIM / 32), 256, 0, stream>>>(wkv_down, wkvd_t, DIM, KVLORA + ROPE);
    transp_kernel<<<dim3(NH * NOPE / 32, QLORA / 32), 256, 0, stream>>>(wq_nope, wqn_t, QLORA, NH * NOPE);
    transp_kernel<<<dim3(NH * ROPE / 32, QLORA / 32), 256, 0, stream>>>(wq_rope, wqr_t, QLORA, NH * ROPE);
    transp_kernel<<<dim3(NH * 256 / 32, KVLORA / 32), 256, 0, stream>>>(wkv_up, wkvu_t, KVLORA, NH * 256);
    transp_kernel<<<dim3(DIM / 32, DIM / 32), 256, 0, stream>>>(wo, wo_t, DIM, DIM);

    // fused down-projection: [3072][2112] = xb @ [wq_down | wkv_down]
    gemm_mfma<<<dim3(17, T_SEQ / 128), 256, 0, stream>>>(xb, DIM, wqd_t, nullptr, ql_kvd, T_SEQ, 2112, DIM, 0);

    rmsnorm_rows<<<T_SEQ, 256, 0, stream>>>(ql_kvd, 2112, q_norm_w, QLORA);
    kv_post<<<T_SEQ, 256, 0, stream>>>(ql_kvd + QLORA, 2112, kv_norm_w, freqs, ckvn, kr);

    // fused q up-projection: [3072][3072] = q_lat @ [wq_nope | wq_rope]
    gemm_mfma<<<dim3(24, T_SEQ / 128), 256, 0, stream>>>(ql_kvd, 2112, wqn_t, nullptr, q_up, T_SEQ, 3072, QLORA, 0);
    rope_q<<<(T_SEQ * NH * 32 + 255) / 256, 256, 0, stream>>>(q_up + 2048, freqs);
    gemm_mfma<<<dim3(32, T_SEQ / 128), 256, 0, stream>>>(ckvn, KVLORA, wkvu_t, nullptr, kvu, T_SEQ, NH * 256, KVLORA, 0);

    // V transpose for attention B-operand
    vt_transp<<<dim3(T_SEQ / 32, VDIM / 32, NH), 256, 0, stream>>>(kvu, vt);

    // split-K barrier-free attention + combine
    attn_v5<<<dim3(T_SEQ / 64, 4, NH), 256, 0, stream>>>(q_up, kvu, kr, vt, Opart, lpart);
    attn_combine<<<dim3(T_SEQ / 64, NH), 256, 0, stream>>>(Opart, lpart, ao);

    // output projection (fp32 out)
    gemm_mfma<<<dim3(DIM / 128, T_SEQ / 128), 256, 0, stream>>>(ao, DIM, wo_t, out, nullptr, T_SEQ, DIM, DIM, 1);
}

// Round 8
// 842.819 us; speedup vs baseline: 1.0835x; 1.0835x over previous
//
#include <hip/hip_runtime.h>
#include <hip/hip_bf16.h>

typedef __bf16 bf16_t;
typedef __bf16 bf16x8 __attribute__((ext_vector_type(8)));
typedef float f32x4 __attribute__((ext_vector_type(4)));

// Problem constants
#define T_SEQ 3072
#define DIM 2048
#define NH 16
#define QLORA 1536
#define KVLORA 512
#define NOPE 128
#define ROPE 64
#define VDIM 128
#define HD 192          // NOPE+ROPE
#define SCALE 0.07216878364870323f  // 192^-0.5
#define CHUNK 12        // k-tiles (of 64 keys) per attention block

// ---------------- helpers ----------------
__device__ inline float wave_reduce_sum(float v) {
    #pragma unroll
    for (int off = 32; off > 0; off >>= 1) v += __shfl_down(v, off);
    return v;
}

__device__ inline float block_reduce_sum_256(float v) {
    __shared__ float red[4];
    int lane = threadIdx.x & 63, w = threadIdx.x >> 6;
    v = wave_reduce_sum(v);
    if (lane == 0) red[w] = v;
    __syncthreads();
    if (threadIdx.x == 0) red[0] = red[0] + red[1] + red[2] + red[3];
    __syncthreads();
    return red[0];
}

// ---------------- fp32 -> bf16 convert ----------------
__global__ void f2b_kernel(const float* __restrict__ in, bf16_t* __restrict__ out, int n) {
    int i = (blockIdx.x * 256 + threadIdx.x) * 4;
    if (i < n) {
        float4 v = *(const float4*)&in[i];
        bf16_t o[4] = {(bf16_t)v.x, (bf16_t)v.y, (bf16_t)v.z, (bf16_t)v.w};
        *(uint2*)&out[i] = *(const uint2*)o;
    }
}

// ---------------- fp32 [K][N] -> bf16 [N][K] transpose-convert ----------------
__global__ __launch_bounds__(256) void transp_kernel(
    const float* __restrict__ in, bf16_t* __restrict__ out, int K, int N)
{
    __shared__ float tile[32][33];
    int k0 = blockIdx.y * 32, n0 = blockIdx.x * 32;
    int tx = threadIdx.x & 31, ty = threadIdx.x >> 5;
    #pragma unroll
    for (int i = 0; i < 4; ++i)
        tile[ty + i * 8][tx] = in[(size_t)(k0 + ty + i * 8) * N + n0 + tx];
    __syncthreads();
    #pragma unroll
    for (int i = 0; i < 4; ++i)
        out[(size_t)(n0 + ty + i * 8) * K + k0 + tx] = (bf16_t)tile[tx][ty + i * 8];
}

// ---------------- bf16 kvu V-part -> vt[h][d][t] transpose ----------------
__global__ __launch_bounds__(256) void vt_transp(
    const bf16_t* __restrict__ kvu, bf16_t* __restrict__ vt)
{
    __shared__ bf16_t tile[32][34];
    int t0 = blockIdx.x * 32, d0 = blockIdx.y * 32, h = blockIdx.z;
    int tx = threadIdx.x & 31, ty = threadIdx.x >> 5;
    #pragma unroll
    for (int i = 0; i < 4; ++i)
        tile[ty + i * 8][tx] = kvu[(size_t)(t0 + ty + i * 8) * (NH * 256) + h * 256 + NOPE + d0 + tx];
    __syncthreads();
    #pragma unroll
    for (int i = 0; i < 4; ++i)
        vt[((size_t)h * VDIM + d0 + ty + i * 8) * T_SEQ + t0 + tx] = tile[tx][ty + i * 8];
}

// ---------------- MFMA GEMM with register-prefetch pipeline ----------------
// C[M,N] = A[M,K](bf16, row stride lda) x Bt[N,K](bf16)
__global__ __launch_bounds__(256) void gemm_mfma(
    const bf16_t* __restrict__ A, int lda, const bf16_t* __restrict__ Bt,
    float* __restrict__ Cf, bf16_t* __restrict__ Cb,
    int M, int N, int K, int writef)
{
    __shared__ __align__(16) bf16_t As[128 * 40];
    __shared__ __align__(16) bf16_t Bs[128 * 40];
    int tid = threadIdx.x;
    int w = tid >> 6, lane = tid & 63;
    int quad = lane >> 4, l16 = lane & 15;
    int bm = blockIdx.y * 128, bn = blockIdx.x * 128;
    int wm = (w & 1) * 64, wn = (w >> 1) * 64;

    // staging coords: cid = tid + l*256, row = cid>>2, ch = cid&3
    const int r0 = tid >> 2, c0 = (tid & 3) * 8;
    const int r1 = (tid + 256) >> 2, c1 = c0;  // same ch pattern
    const bf16_t* pa0 = &A[(size_t)(bm + r0) * lda + c0];
    const bf16_t* pa1 = &A[(size_t)(bm + r1) * lda + c1];
    const bf16_t* pb0 = &Bt[(size_t)min(bn + r0, N - 1) * K + c0];
    const bf16_t* pb1 = &Bt[(size_t)min(bn + r1, N - 1) * K + c1];
    const bool okb0 = (bn + r0) < N, okb1 = (bn + r1) < N;
    const int lo0 = r0 * 40 + c0, lo1 = r1 * 40 + c1;

    f32x4 acc[4][4];
    #pragma unroll
    for (int i = 0; i < 4; ++i)
        #pragma unroll
        for (int j = 0; j < 4; ++j)
            acc[i][j] = (f32x4){0.f, 0.f, 0.f, 0.f};

    // prologue: stage k0=0
    {
        uint4 a0 = *(const uint4*)&pa0[0];
        uint4 a1 = *(const uint4*)&pa1[0];
        uint4 b0 = okb0 ? *(const uint4*)&pb0[0] : (uint4){0u,0u,0u,0u};
        uint4 b1 = okb1 ? *(const uint4*)&pb1[0] : (uint4){0u,0u,0u,0u};
        *(uint4*)&As[lo0] = a0; *(uint4*)&As[lo1] = a1;
        *(uint4*)&Bs[lo0] = b0; *(uint4*)&Bs[lo1] = b1;
    }
    __syncthreads();

    for (int k0 = 0; k0 < K; k0 += 32) {
        uint4 na0, na1, nb0, nb1;
        bool more = (k0 + 32) < K;
        if (more) {
            na0 = *(const uint4*)&pa0[k0 + 32];
            na1 = *(const uint4*)&pa1[k0 + 32];
            nb0 = okb0 ? *(const uint4*)&pb0[k0 + 32] : (uint4){0u,0u,0u,0u};
            nb1 = okb1 ? *(const uint4*)&pb1[k0 + 32] : (uint4){0u,0u,0u,0u};
        }
        bf16x8 af[4], bfr[4];
        #pragma unroll
        for (int t = 0; t < 4; ++t) {
            af[t]  = *(const bf16x8*)&As[(wm + t * 16 + l16) * 40 + quad * 8];
            bfr[t] = *(const bf16x8*)&Bs[(wn + t * 16 + l16) * 40 + quad * 8];
        }
        #pragma unroll
        for (int i = 0; i < 4; ++i)
            #pragma unroll
            for (int j = 0; j < 4; ++j)
                acc[i][j] = __builtin_amdgcn_mfma_f32_16x16x32_bf16(af[i], bfr[j], acc[i][j], 0, 0, 0);
        if (more) {
            __syncthreads();   // all waves done reading LDS
            *(uint4*)&As[lo0] = na0; *(uint4*)&As[lo1] = na1;
            *(uint4*)&Bs[lo0] = nb0; *(uint4*)&Bs[lo1] = nb1;
            __syncthreads();   // next tile visible
        }
    }

    #pragma unroll
    for (int i = 0; i < 4; ++i) {
        #pragma unroll
        for (int j = 0; j < 4; ++j) {
            #pragma unroll
            for (int r = 0; r < 4; ++r) {
                int row = bm + wm + i * 16 + quad * 4 + r;
                int col = bn + wn + j * 16 + l16;
                if (col < N) {
                    if (writef) Cf[(size_t)row * N + col] = acc[i][j][r];
                    else        Cb[(size_t)row * N + col] = (bf16_t)acc[i][j][r];
                }
            }
        }
    }
}

// ---------------- rmsnorm in-place over strided rows ----------------
__global__ __launch_bounds__(256) void rmsnorm_rows(
    bf16_t* __restrict__ X, int stride, const float* __restrict__ w, int N)
{
    int row = blockIdx.x;
    bf16_t* x = X + (size_t)row * stride;
    float ss = 0.f;
    for (int i = threadIdx.x; i < N; i += 256) { float v = (float)x[i]; ss += v * v; }
    ss = block_reduce_sum_256(ss);
    float sc = rsqrtf(ss / (float)N + 1e-6f);
    for (int i = threadIdx.x; i < N; i += 256)
        x[i] = (bf16_t)((float)x[i] * sc * w[i]);
}

// ---------------- kv post ----------------
__global__ __launch_bounds__(256) void kv_post(
    const bf16_t* __restrict__ kvd, int stride, const float* __restrict__ w,
    const float* __restrict__ freqs,
    bf16_t* __restrict__ ckvn, bf16_t* __restrict__ kr)
{
    int row = blockIdx.x;
    const bf16_t* src = kvd + (size_t)row * stride;
    float ss = 0.f;
    for (int i = threadIdx.x; i < KVLORA; i += 256) { float v = (float)src[i]; ss += v * v; }
    ss = block_reduce_sum_256(ss);
    float sc = rsqrtf(ss / (float)KVLORA + 1e-6f);
    for (int i = threadIdx.x; i < KVLORA; i += 256)
        ckvn[(size_t)row * KVLORA + i] = (bf16_t)((float)src[i] * sc * w[i]);
    if (threadIdx.x < 32) {
        int i = threadIdx.x;
        float f = freqs[row * 32 + i];
        float c = cosf(f), s = sinf(f);
        float x1 = (float)src[KVLORA + 2 * i], x2 = (float)src[KVLORA + 2 * i + 1];
        kr[(size_t)row * ROPE + 2 * i]     = (bf16_t)(x1 * c - x2 * s);
        kr[(size_t)row * ROPE + 2 * i + 1] = (bf16_t)(x1 * s + x2 * c);
    }
}

// ---------------- rope on q_rope view (row stride 3072) ----------------
__global__ void rope_q(bf16_t* __restrict__ qr, const float* __restrict__ freqs) {
    int idx = blockIdx.x * 256 + threadIdx.x;
    if (idx >= T_SEQ * NH * 32) return;
    int t = idx >> 9;
    int rem = idx & 511;
    int h = rem >> 5;
    int i = rem & 31;
    float f = freqs[t * 32 + i];
    float c = cosf(f), s = sinf(f);
    bf16_t* p = qr + (size_t)t * 3072 + h * ROPE + 2 * i;
    float x1 = (float)p[0], x2 = (float)p[1];
    p[0] = (bf16_t)(x1 * c - x2 * s);
    p[1] = (bf16_t)(x1 * s + x2 * c);
}

// ---------------- split-K MFMA flash attention with prefetch pipeline ----------------
// grid (48 qt, 4 chunk, 16 h), block 256 (4 waves). LDS-staged K, but tile kt+1's
// global loads are issued BEFORE computing tile kt (vmcnt wait lands after compute).
#define KS_STRIDE 200   // 192+8 bf16
#define P_STRIDE 72     // 64+8 bf16
__device__ inline int slot_base(int qt, int h) {
    int b = qt / CHUNK;
    return h * 120 + qt + 6 * b * (b - 1) + (qt - CHUNK * b) * b;
}
__global__ __launch_bounds__(256) void attn_v6(
    const bf16_t* __restrict__ Qup,   // [T][3072]: 0..2047 q_nope, 2048.. q_rope
    const bf16_t* __restrict__ KVU, const bf16_t* __restrict__ KR,
    const bf16_t* __restrict__ Vt,
    bf16_t* __restrict__ Opart, float* __restrict__ lpart)
{
    __shared__ __align__(16) bf16_t Ks[64 * KS_STRIDE];   // 25600 B
    __shared__ __align__(16) bf16_t Ps[4][16 * P_STRIDE]; //  9216 B

    int qt = blockIdx.x, cx = blockIdx.y, h = blockIdx.z;
    if (cx > qt / CHUNK) return;
    int slot = slot_base(qt, h) + cx;
    int kt0 = cx * CHUNK;
    int kt1 = min(qt + 1, kt0 + CHUNK);

    int tid = threadIdx.x;
    int w = tid >> 6, lane = tid & 63;
    int quad = lane >> 4, l16 = lane & 15;
    int qbase = qt * 64;

    // per-thread K staging coords (6 chunks: cid = tid + l*256; row=cid/24, ch=cid%24)
    const bf16_t* sbase[6];
    int sstep[6], soff[6];
    #pragma unroll
    for (int l = 0; l < 6; ++l) {
        int cid = tid + l * 256;
        int row = cid / 24, ch = cid % 24;
        if (ch < 16) { sbase[l] = &KVU[(size_t)row * (NH * 256) + h * 256 + ch * 8]; sstep[l] = NH * 256; }
        else         { sbase[l] = &KR[(size_t)row * ROPE + (ch - 16) * 8];           sstep[l] = ROPE; }
        soff[l] = row * KS_STRIDE + ch * 8;
    }

    // Q fragments from global into registers
    bf16x8 qf[6];
    {
        const bf16_t* qp = &Qup[(size_t)(qbase + w * 16 + l16) * 3072];
        #pragma unroll
        for (int kk = 0; kk < 4; ++kk)
            qf[kk] = *(const bf16x8*)&qp[h * NOPE + kk * 32 + quad * 8];
        #pragma unroll
        for (int kk = 4; kk < 6; ++kk)
            qf[kk] = *(const bf16x8*)&qp[2048 + h * ROPE + (kk - 4) * 32 + quad * 8];
    }

    bf16x8 ones;
    #pragma unroll
    for (int i = 0; i < 8; ++i) ones[i] = (bf16_t)1.0f;

    f32x4 o[8];
    #pragma unroll
    for (int nt = 0; nt < 8; ++nt) o[nt] = (f32x4){0.f, 0.f, 0.f, 0.f};
    f32x4 lacc = (f32x4){0.f, 0.f, 0.f, 0.f};

    // prologue: stage tile kt0
    {
        int kbase = kt0 * 64;
        #pragma unroll
        for (int l = 0; l < 6; ++l)
            *(uint4*)&Ks[soff[l]] = *(const uint4*)&sbase[l][(size_t)kbase * sstep[l]];
    }
    __syncthreads();

    for (int kt = kt0; kt < kt1; ++kt) {
        int kbase = kt * 64;
        // prefetch next tile into registers (no wait until LDS write below)
        uint4 st[6];
        bool more = (kt + 1) < kt1;
        if (more) {
            int nb = kbase + 64;
            #pragma unroll
            for (int l = 0; l < 6; ++l)
                st[l] = *(const uint4*)&sbase[l][(size_t)nb * sstep[l]];
        }

        // S = Q K^T : 4 col-tiles x 6 k-steps from LDS
        f32x4 S[4];
        #pragma unroll
        for (int c = 0; c < 4; ++c) S[c] = (f32x4){0.f, 0.f, 0.f, 0.f};
        #pragma unroll
        for (int kk = 0; kk < 6; ++kk) {
            #pragma unroll
            for (int c = 0; c < 4; ++c) {
                bf16x8 kf = *(const bf16x8*)&Ks[(c * 16 + l16) * KS_STRIDE + kk * 32 + quad * 8];
                S[c] = __builtin_amdgcn_mfma_f32_16x16x32_bf16(qf[kk], kf, S[c], 0, 0, 0);
            }
        }

        // fixed-max softmax: p = exp(s*SCALE)
        #pragma unroll
        for (int c = 0; c < 4; ++c) {
            #pragma unroll
            for (int j = 0; j < 4; ++j) {
                int col = kbase + c * 16 + l16;
                int grow = qbase + w * 16 + quad * 4 + j;
                float p = (col <= grow) ? __expf(S[c][j] * SCALE) : 0.f;
                Ps[w][(quad * 4 + j) * P_STRIDE + c * 16 + l16] = (bf16_t)p;
            }
        }
        __asm__ volatile("s_waitcnt lgkmcnt(0)" ::: "memory");

        bf16x8 pf0 = *(const bf16x8*)&Ps[w][l16 * P_STRIDE + quad * 8];
        bf16x8 pf1 = *(const bf16x8*)&Ps[w][l16 * P_STRIDE + 32 + quad * 8];
        lacc = __builtin_amdgcn_mfma_f32_16x16x32_bf16(pf0, ones, lacc, 0, 0, 0);
        lacc = __builtin_amdgcn_mfma_f32_16x16x32_bf16(pf1, ones, lacc, 0, 0, 0);

        // O += P V : V fragments direct from global vt[h][d][t]
        #pragma unroll
        for (int kk2 = 0; kk2 < 2; ++kk2) {
            bf16x8 pf = kk2 ? pf1 : pf0;
            #pragma unroll
            for (int nt = 0; nt < 8; ++nt) {
                bf16x8 vf = *(const bf16x8*)&Vt[((size_t)h * VDIM + nt * 16 + l16) * T_SEQ + kbase + kk2 * 32 + quad * 8];
                o[nt] = __builtin_amdgcn_mfma_f32_16x16x32_bf16(pf, vf, o[nt], 0, 0, 0);
            }
        }

        if (more) {
            __syncthreads();   // all waves done reading Ks
            #pragma unroll
            for (int l = 0; l < 6; ++l)
                *(uint4*)&Ks[soff[l]] = st[l];   // compiler inserts vmcnt wait here
            __syncthreads();   // new tile visible
        }
    }

    // write raw partials
    #pragma unroll
    for (int nt = 0; nt < 8; ++nt)
        #pragma unroll
        for (int j = 0; j < 4; ++j)
            Opart[(size_t)slot * 8192 + (w * 16 + quad * 4 + j) * 128 + nt * 16 + l16] = (bf16_t)o[nt][j];
    if (l16 == 0) {
        #pragma unroll
        for (int j = 0; j < 4; ++j)
            lpart[slot * 64 + w * 16 + quad * 4 + j] = lacc[j];
    }
}

// ---------------- combine: sum partials, normalize, write ao ----------------
__global__ __launch_bounds__(256) void attn_combine(
    const bf16_t* __restrict__ Opart, const float* __restrict__ lpart,
    bf16_t* __restrict__ AO)
{
    int qt = blockIdx.x, h = blockIdx.y;
    int nch = qt / CHUNK + 1;
    int base = slot_base(qt, h);
    int r = threadIdx.x >> 2, c0 = (threadIdx.x & 3) * 32;

    float acc[32];
    #pragma unroll
    for (int i = 0; i < 32; ++i) acc[i] = 0.f;
    float lsum = 0.f;
    for (int ch = 0; ch < nch; ++ch) {
        int slot = base + ch;
        const bf16_t* p = &Opart[(size_t)slot * 8192 + r * 128 + c0];
        #pragma unroll
        for (int v = 0; v < 4; ++v) {
            bf16x8 u = *(const bf16x8*)&p[v * 8];
            #pragma unroll
            for (int e = 0; e < 8; ++e) acc[v * 8 + e] += (float)u[e];
        }
        lsum += lpart[slot * 64 + r];
    }
    float inv = 1.0f / lsum;
    bf16_t* dst = AO + (size_t)(qt * 64 + r) * (NH * VDIM) + h * VDIM + c0;
    #pragma unroll
    for (int v = 0; v < 4; ++v) {
        bf16_t tmp[8];
        #pragma unroll
        for (int e = 0; e < 8; ++e) tmp[e] = (bf16_t)(acc[v * 8 + e] * inv);
        *(uint4*)&dst[v * 8] = *(const uint4*)tmp;
    }
}

// ---------------- launch ----------------
extern "C" void kernel_launch(void* const* d_in, const int* in_sizes, int n_in,
                              void* d_out, int out_size, void* d_ws, size_t ws_size,
                              hipStream_t stream) {
    const float* x        = (const float*)d_in[0];
    const float* freqs    = (const float*)d_in[1];
    // d_in[2] = mask (unused; causality applied analytically)
    const float* wq_down  = (const float*)d_in[3];
    const float* q_norm_w = (const float*)d_in[4];
    const float* wq_nope  = (const float*)d_in[5];
    const float* wq_rope  = (const float*)d_in[6];
    const float* wkv_down = (const float*)d_in[7];
    const float* kv_norm_w= (const float*)d_in[8];
    const float* wkv_up   = (const float*)d_in[9];
    const float* wo       = (const float*)d_in[10];
    float* out = (float*)d_out;

    bf16_t* ws = (bf16_t*)d_ws;
    // ---- pool region (two time-disjoint views), 25,493,504 bf16 elems ----
    bf16_t* xb     = ws;                     // 3072*2048
    bf16_t* wqd_t  = xb     + 6291456;       // [1536][2048]  \ combined Bt [2112][2048]
    bf16_t* wkvd_t = wqd_t  + 3145728;       // [576][2048]   /
    bf16_t* wqn_t  = wkvd_t + 1179648;       // [2048][1536]  \ combined Bt [3072][1536]
    bf16_t* wqr_t  = wqn_t  + 3145728;       // [1024][1536]  /
    bf16_t* wkvu_t = wqr_t  + 1572864;       // [4096][512]
    bf16_t* ql_kvd = wkvu_t + 2097152;       // [3072][2112] (q_lat | kvd)
    bf16_t* ckvn   = ql_kvd + 6488064;       // 3072*512
    // B-view: attention partials + ao
    bf16_t* Opart  = ws;                     // 1920 slots * 8192
    float*  lpart  = (float*)(ws + 15728640);// 1920 * 64 fp32
    bf16_t* ao     = ws + 15728640 + 245760; // 3072*2048
    // ---- tail region (long-lived) ----
    bf16_t* wo_t   = ws    + 25493504;       // [2048][2048]
    bf16_t* kr     = wo_t  + 4194304;        // 3072*64
    bf16_t* q_up   = kr    + 196608;         // [3072][3072] (q_nope | q_rope)
    bf16_t* kvu    = q_up  + 9437184;        // 3072*4096
    bf16_t* vt     = kvu   + 12582912;       // [16][128][3072]

    // converts + weight transposes
    f2b_kernel<<<T_SEQ * DIM / 4 / 256, 256, 0, stream>>>(x, xb, T_SEQ * DIM);
    transp_kernel<<<dim3(QLORA / 32, DIM / 32), 256, 0, stream>>>(wq_down, wqd_t, DIM, QLORA);
    transp_kernel<<<dim3((KVLORA + ROPE) / 32, DIM / 32), 256, 0, stream>>>(wkv_down, wkvd_t, DIM, KVLORA + ROPE);
    transp_kernel<<<dim3(NH * NOPE / 32, QLORA / 32), 256, 0, stream>>>(wq_nope, wqn_t, QLORA, NH * NOPE);
    transp_kernel<<<dim3(NH * ROPE / 32, QLORA / 32), 256, 0, stream>>>(wq_rope, wqr_t, QLORA, NH * ROPE);
    transp_kernel<<<dim3(NH * 256 / 32, KVLORA / 32), 256, 0, stream>>>(wkv_up, wkvu_t, KVLORA, NH * 256);
    transp_kernel<<<dim3(DIM / 32, DIM / 32), 256, 0, stream>>>(wo, wo_t, DIM, DIM);

    // fused down-projection: [3072][2112] = xb @ [wq_down | wkv_down]
    gemm_mfma<<<dim3(17, T_SEQ / 128), 256, 0, stream>>>(xb, DIM, wqd_t, nullptr, ql_kvd, T_SEQ, 2112, DIM, 0);

    rmsnorm_rows<<<T_SEQ, 256, 0, stream>>>(ql_kvd, 2112, q_norm_w, QLORA);
    kv_post<<<T_SEQ, 256, 0, stream>>>(ql_kvd + QLORA, 2112, kv_norm_w, freqs, ckvn, kr);

    // fused q up-projection: [3072][3072] = q_lat @ [wq_nope | wq_rope]
    gemm_mfma<<<dim3(24, T_SEQ / 128), 256, 0, stream>>>(ql_kvd, 2112, wqn_t, nullptr, q_up, T_SEQ, 3072, QLORA, 0);
    rope_q<<<(T_SEQ * NH * 32 + 255) / 256, 256, 0, stream>>>(q_up + 2048, freqs);
    gemm_mfma<<<dim3(32, T_SEQ / 128), 256, 0, stream>>>(ckvn, KVLORA, wkvu_t, nullptr, kvu, T_SEQ, NH * 256, KVLORA, 0);

    // V transpose for attention B-operand
    vt_transp<<<dim3(T_SEQ / 32, VDIM / 32, NH), 256, 0, stream>>>(kvu, vt);

    // split-K attention (prefetch pipeline) + combine
    attn_v6<<<dim3(T_SEQ / 64, 4, NH), 256, 0, stream>>>(q_up, kvu, kr, vt, Opart, lpart);
    attn_combine<<<dim3(T_SEQ / 64, NH), 256, 0, stream>>>(Opart, lpart, ao);

    // output projection (fp32 out)
    gemm_mfma<<<dim3(DIM / 128, T_SEQ / 128), 256, 0, stream>>>(ao, DIM, wo_t, out, nullptr, T_SEQ, DIM, DIM, 1);
}